// Round 6
// baseline (2937.722 us; speedup 1.0000x reference)
//
#include <hip/hip_runtime.h>
#include <math.h>

// Problem constants
#define BB   128      // batch
#define TT   25       // time steps
#define RR   100      // attention regions
#define DD   512
#define VV   10000
#define NG   2048     // 4*H
#define PAD  8        // LDS pad (bf16 elems) for gemm_mfma

typedef short bf8   __attribute__((ext_vector_type(8)));  // 8 bf16 in 4 VGPRs
typedef float f32x4 __attribute__((ext_vector_type(4)));

__device__ __forceinline__ float sigm(float x) { return 1.f / (1.f + expf(-x)); }

__device__ __forceinline__ short f2bf(float f) {        // RNE f32 -> bf16
  unsigned u = __float_as_uint(f);
  u += 0x7fffu + ((u >> 16) & 1u);
  return (short)(u >> 16);
}
__device__ __forceinline__ float bf2f(short h) {
  return __uint_as_float(((unsigned)(unsigned short)h) << 16);
}

// ============ init: scatter initial hidden state ============
// h0_init -> CCH1[0:512) (read by prologue z0); h1_init -> CCH0[1024:1536)
// (read by z1 at t=0). c0/c1 -> C0/C1. Also zero the barrier flags (2048 ints).
__global__ __launch_bounds__(256) void k_init(const float* __restrict__ ihs,
                                              short* __restrict__ CCH0,
                                              short* __restrict__ CCH1,
                                              float* __restrict__ C0,
                                              float* __restrict__ C1,
                                              int* __restrict__ bar) {
  int idx = blockIdx.x * 256 + threadIdx.x;     // < 262144
  if (idx < 2048) bar[idx] = 0;
  int s = idx >> 17, r = idx & 131071, b = r >> 10, j = r & 1023;
  float v = ihs[idx];
  if (s == 0) {
    if (j < 512) CCH1[b * 1536 + j] = f2bf(v);
    else         C0[b * 512 + (j - 512)] = v;
  } else {
    if (j < 512) CCH0[b * 1536 + 1024 + j] = f2bf(v);
    else         C1[b * 512 + (j - 512)] = v;
  }
}

// ============ cnn pooled: max over first 10 regions ============
__global__ __launch_bounds__(256) void k_pool(const float* __restrict__ feat,
                                              float* __restrict__ pool) {
  int idx = blockIdx.x * 256 + threadIdx.x;     // < 65536
  int b = idx >> 9, d = idx & 511;
  float m = -3.4e38f;
  #pragma unroll
  for (int r = 0; r < 10; r++)
    m = fmaxf(m, feat[((size_t)b * RR + r) * 512 + d]);
  pool[idx] = m;
}

// ============ Xin (3200 x 1024 bf16): [emb(tok[b,t]) | pooled[b]], row m=t*128+b
__global__ __launch_bounds__(256) void k_xin(const int* __restrict__ tok,
                                             const float* __restrict__ emb,
                                             const float* __restrict__ pool,
                                             short* __restrict__ xin) {
  int idx = blockIdx.x * 256 + threadIdx.x;     // < 3,276,800
  int m = idx >> 10, k = idx & 1023;
  int t = m >> 7, b = m & 127;
  float v;
  if (k < 512) v = emb[(size_t)tok[b * TT + t] * 512 + k];
  else         v = pool[b * 512 + (k - 512)];
  xin[idx] = f2bf(v);
}

// ============ tiled transpose + f32->bf16: in (K x N) -> out (N x K) ============
__global__ __launch_bounds__(256) void k_transpose(const float* __restrict__ in,
                                                   short* __restrict__ out,
                                                   int K, int N) {
  __shared__ float tile[32][33];
  int kt = blockIdx.y * 32, nt = blockIdx.x * 32;
  int tx = threadIdx.x & 31, ty = threadIdx.x >> 5;   // 32 x 8
  #pragma unroll
  for (int i = 0; i < 32; i += 8) {
    int k = kt + ty + i, n = nt + tx;
    tile[ty + i][tx] = (n < N) ? in[(size_t)k * N + n] : 0.f;
  }
  __syncthreads();
  #pragma unroll
  for (int i = 0; i < 32; i += 8) {
    int n = nt + ty + i, k = kt + tx;
    if (n < N) out[(size_t)n * K + k] = f2bf(tile[tx][ty + i]);
  }
}

// same, f32 out (for attn_W so score dot stays f32 and reads are contiguous)
__global__ __launch_bounds__(256) void k_transpose_f32(const float* __restrict__ in,
                                                       float* __restrict__ out,
                                                       int K, int N) {
  __shared__ float tile[32][33];
  int kt = blockIdx.y * 32, nt = blockIdx.x * 32;
  int tx = threadIdx.x & 31, ty = threadIdx.x >> 5;
  #pragma unroll
  for (int i = 0; i < 32; i += 8) {
    int k = kt + ty + i, n = nt + tx;
    tile[ty + i][tx] = (n < N) ? in[(size_t)k * N + n] : 0.f;
  }
  __syncthreads();
  #pragma unroll
  for (int i = 0; i < 32; i += 8) {
    int n = nt + ty + i, k = kt + tx;
    if (n < N) out[(size_t)n * K + k] = tile[tx][ty + i];
  }
}

// ============ big MFMA GEMM: C(MxN f32) = A(MxK bf16) @ BT(NxK bf16)^T + bias
// 128x128 tile, BK=64, 256 thr / 4 waves, each wave 64x64 (4x4 frags 16x16x32).
// mode 0: C[m*ldc+n] = acc+bias   mode 1: logits remap out[b*T*V + t*V + n]
__global__ __launch_bounds__(256) void gemm_mfma(
    const short* __restrict__ A, int lda,
    const short* __restrict__ BT, int ldb,
    const float* __restrict__ bias,
    float* __restrict__ C, int ldc,
    int N, int K, int mode) {
  __shared__ short As[128][64 + PAD];
  __shared__ short Bs[128][64 + PAD];
  const int tid = threadIdx.x;
  const int wv = tid >> 6, ln = tid & 63;
  const int m0 = blockIdx.y * 128, n0 = blockIdx.x * 128;
  const int mw = (wv & 1) * 64, nw = (wv >> 1) * 64;
  const int lrow = ln & 15, quad = ln >> 4, lk8 = quad * 8;

  f32x4 acc[4][4] = {};
  for (int k0 = 0; k0 < K; k0 += 64) {
    #pragma unroll
    for (int v = 0; v < 4; v++) {                 // A: 128x64 = 1024 vecs
      int f = v * 256 + tid, r = f >> 3, kk = (f & 7) * 8;
      *(uint4*)&As[r][kk] = *(const uint4*)&A[(size_t)(m0 + r) * lda + k0 + kk];
    }
    #pragma unroll
    for (int v = 0; v < 4; v++) {                 // B^T: 128 n-rows x 64 k
      int f = v * 256 + tid, r = f >> 3, kk = (f & 7) * 8;
      int n = n0 + r;
      uint4 val{0, 0, 0, 0};
      if (n < N) val = *(const uint4*)&BT[(size_t)n * ldb + k0 + kk];
      *(uint4*)&Bs[r][kk] = val;
    }
    __syncthreads();
    #pragma unroll
    for (int ks = 0; ks < 64; ks += 32) {
      bf8 af[4], bf[4];
      #pragma unroll
      for (int i = 0; i < 4; i++)
        af[i] = *(const bf8*)&As[mw + i * 16 + lrow][ks + lk8];
      #pragma unroll
      for (int j = 0; j < 4; j++)
        bf[j] = *(const bf8*)&Bs[nw + j * 16 + lrow][ks + lk8];
      #pragma unroll
      for (int i = 0; i < 4; i++)
        #pragma unroll
        for (int j = 0; j < 4; j++)
          acc[i][j] = __builtin_amdgcn_mfma_f32_16x16x32_bf16(
              af[i], bf[j], acc[i][j], 0, 0, 0);
    }
    __syncthreads();
  }
  #pragma unroll
  for (int i = 0; i < 4; i++) {
    #pragma unroll
    for (int j = 0; j < 4; j++) {
      #pragma unroll
      for (int r = 0; r < 4; r++) {
        int m = m0 + mw + i * 16 + quad * 4 + r;
        int n = n0 + nw + j * 16 + lrow;
        if (n < N) {
          float v = acc[i][j][r] + (bias ? bias[n] : 0.f);
          if (mode == 0) C[(size_t)m * ldc + n] = v;
          else {
            int t = m >> 7, b = m & 127;
            C[(size_t)b * (TT * VV) + (size_t)t * VV + n] = v;
          }
        }
      }
    }
  }
}

// ============ z-phase building blocks (MACROS — no LDS ptr crosses functions).
// Block (m0 = 32-row batch slice, j0 = 16-col hidden slice) computes z for ALL
// 4 gates (n = g*512 + j0..j0+15) over full K, K staged in 256-wide chunks with
// a depth-2 register prefetch pipeline (pa0/pb0, pa1/pb1 alternate).
#define LP_ISSUE(PA, PB, APTR, BTPTR, KTOT, KC)                               \
    _Pragma("unroll")                                                         \
    for (int v = 0; v < 4; v++) {               /* A: 32 x 256 */             \
      int f = v * 256 + tid, r = f >> 5, cc = (f & 31) * 8;                   \
      PA[v] = *(const uint4*)&(APTR)[(size_t)(m0 + r) * 1536 + (KC) + cc];    \
    }                                                                         \
    _Pragma("unroll")                                                         \
    for (int v = 0; v < 8; v++) {               /* B^T gate-sliced: 64x256 */ \
      int f = v * 256 + tid, r = f >> 5, cc = (f & 31) * 8;                   \
      int n = ((r >> 4) << 9) + j0 + (r & 15);                                \
      PB[v] = *(const uint4*)&(BTPTR)[(size_t)n * (KTOT) + (KC) + cc];        \
    }

#define LP_STAGE(PA, PB)                                                      \
    _Pragma("unroll")                                                         \
    for (int v = 0; v < 4; v++) {                                             \
      int f = v * 256 + tid, r = f >> 5, cc = (f & 31) * 8;                   \
      *(uint4*)&As[r][cc] = PA[v];                                            \
    }                                                                         \
    _Pragma("unroll")                                                         \
    for (int v = 0; v < 8; v++) {                                             \
      int f = v * 256 + tid, r = f >> 5, cc = (f & 31) * 8;                   \
      *(uint4*)&Bs[r][cc] = PB[v];                                            \
    }                                                                         \
    __syncthreads();

#define LP_MFMA()                                                             \
    _Pragma("unroll")                                                         \
    for (int ks = 0; ks < 256; ks += 32) {      /* wave wv owns gate wv */    \
      bf8 a0 = *(const bf8*)&As[lrow][ks + lk8];                              \
      bf8 a1 = *(const bf8*)&As[16 + lrow][ks + lk8];                         \
      bf8 bb = *(const bf8*)&Bs[wv * 16 + lrow][ks + lk8];                    \
      acc0 = __builtin_amdgcn_mfma_f32_16x16x32_bf16(a0, bb, acc0, 0, 0, 0);  \
      acc1 = __builtin_amdgcn_mfma_f32_16x16x32_bf16(a1, bb, acc1, 0, 0, 0);  \
    }                                                                         \
    __syncthreads();

// Full fused GEMM + LSTM activation. HAS_X: 1 -> add XROW (incl b0), 0 -> BIASP.
#define LSTM_PHASE(APTR, BTPTR, KTOT, HAS_X, XROW, BIASP, CSTP, HDSTP,        \
                   H0FP, H1ATP)                                               \
  {                                                                           \
    f32x4 acc0 = {}, acc1 = {};                                               \
    uint4 pa0[4], pb0[8], pa1[4], pb1[8];                                     \
    LP_ISSUE(pa0, pb0, APTR, BTPTR, KTOT, 0)                                  \
    LP_ISSUE(pa1, pb1, APTR, BTPTR, KTOT, 256)                                \
    LP_STAGE(pa0, pb0)                                                        \
    if ((KTOT) > 512) { LP_ISSUE(pa0, pb0, APTR, BTPTR, KTOT, 512) }          \
    LP_MFMA()                                                                 \
    LP_STAGE(pa1, pb1)                                                        \
    if ((KTOT) > 512) { LP_ISSUE(pa1, pb1, APTR, BTPTR, KTOT, 768) }          \
    LP_MFMA()                                                                 \
    if ((KTOT) > 512) {                                                       \
      LP_STAGE(pa0, pb0)                                                      \
      LP_ISSUE(pa0, pb0, APTR, BTPTR, KTOT, 1024)                             \
      LP_MFMA()                                                               \
      LP_STAGE(pa1, pb1)                                                      \
      LP_ISSUE(pa1, pb1, APTR, BTPTR, KTOT, 1280)                             \
      LP_MFMA()                                                               \
      LP_STAGE(pa0, pb0)                                                      \
      LP_MFMA()                                                               \
      LP_STAGE(pa1, pb1)                                                      \
      LP_MFMA()                                                               \
    }                                                                         \
    _Pragma("unroll")                                                         \
    for (int r = 0; r < 4; r++) {                                             \
      zs[wv * 512 + (quad * 4 + r) * 16 + lrow] = acc0[r];                    \
      zs[wv * 512 + (16 + quad * 4 + r) * 16 + lrow] = acc1[r];               \
    }                                                                         \
    __syncthreads();                                                          \
    _Pragma("unroll")                                                         \
    for (int e = 0; e < 2; e++) {               /* 512 outputs, 2/thread */   \
      int o = e * 256 + tid, mm = o >> 4, jj = o & 15;                        \
      int b = m0 + mm, j = j0 + jj;                                           \
      float zi = zs[mm * 16 + jj];                                            \
      float zf = zs[512 + mm * 16 + jj];                                      \
      float zo = zs[1024 + mm * 16 + jj];                                     \
      float zg = zs[1536 + mm * 16 + jj];                                     \
      if (HAS_X) {                                                            \
        const float* q = (XROW) + (size_t)b * NG + j;                         \
        zi += q[0]; zf += q[512]; zo += q[1024]; zg += q[1536];               \
      } else {                                                                \
        zi += (BIASP)[j];        zf += (BIASP)[512 + j];                      \
        zo += (BIASP)[1024 + j]; zg += (BIASP)[1536 + j];                     \
      }                                                                       \
      float c  = (CSTP)[b * 512 + j];                                         \
      float cn = sigm(zf) * c + sigm(zi) * tanhf(zg);                         \
      float hn = sigm(zo) * tanhf(cn);                                        \
      (CSTP)[b * 512 + j] = cn;                                               \
      short hb = f2bf(hn);                                                    \
      (HDSTP)[b * 1536 + j] = hb;                                             \
      if (H0FP)  ((float*)(H0FP))[b * 512 + j] = hn;                          \
      if (H1ATP) ((short*)(H1ATP))[(size_t)b * 512 + j] = hb;                 \
    }                                                                         \
    __syncthreads();                                                          \
  }

// ---- grid barrier: per-block flag array, NO RMW. Block bid stores phase to
// its own cacheline (release, agent scope); threads 0..127 each poll one flag.
// Monotonic (>= check), no reset; k_init zeroes flags each launch.
#define GSYNC()                                                               \
  {                                                                           \
    phase++;                                                                  \
    __syncthreads();                                                          \
    if (tid == 0) {                                                           \
      __threadfence();                                                        \
      __hip_atomic_store(&bar[bid * 16], phase, __ATOMIC_RELEASE,             \
                         __HIP_MEMORY_SCOPE_AGENT);                           \
    }                                                                         \
    if (tid < 128) {                                                          \
      while (__hip_atomic_load(&bar[tid * 16], __ATOMIC_ACQUIRE,              \
                               __HIP_MEMORY_SCOPE_AGENT) < phase) {}          \
      __threadfence();                                                        \
    }                                                                         \
    __syncthreads();                                                          \
  }

// ============ persistent t-loop: 1 plain launch, 128 co-resident blocks ======
// Buffers: buf(t) = (t&1)?CCH1:CCH0 holds [h0(t)|ctx(t)|h1(t-1)].
// Per step: [attn] gsync [z1+act1 ; z0(t+1)+act0] gsync  (z0(0) = prologue).
// act1 writes h1(t) into buf(t+1)[1024+]; act0 writes h0(t+1) into buf(t+1)[0+].
__global__ __launch_bounds__(256) void k_loop(
    const float* X0, const short* W0hT, const short* W1T, const float* b1,
    const float* aWT, const float* ab, const float* feat,
    short* CCH0, short* CCH1, float* C0, float* C1,
    float* H0F, short* H1A, int* bar) {
  __shared__ short As[32][264];
  __shared__ short Bs[64][264];
  __shared__ float zs[2048];
  __shared__ float attn_s[1408];   // s0s(1024) | sc(256) | al(128)
  const int tid = threadIdx.x, bid = blockIdx.x;
  const int m0 = (bid >> 5) * 32, j0 = (bid & 31) * 16;
  const int wv = tid >> 6, ln = tid & 63;
  const int lrow = ln & 15, quad = ln >> 4, lk8 = quad * 8;
  int phase = 0;

  // prologue: z0(0)+act0  (A = h0_init in CCH1[0:512), writes h0(0)->CCH0, H0F)
  LSTM_PHASE(CCH1, W0hT, 512, 1, X0, b1, C0, CCH0, H0F, (short*)0);
  GSYNC();

  #pragma unroll 1
  for (int t = 0; t < TT; t++) {
    short* CCHp = (t & 1) ? CCH1 : CCH0;   // buf(t)
    short* CCHq = (t & 1) ? CCH0 : CCH1;   // buf(t+1)

    // ---- attention: block bid handles batch b = bid ----
    {
      float* s0s = attn_s;                 // 1024
      float* sc  = attn_s + 1024;          // 256
      float* al  = attn_s + 1280;          // 128
      int b = bid;
      #pragma unroll
      for (int h = 0; h < 2; h++) {
        int j = h * 256 + tid;
        s0s[j]       = H0F[b * 512 + j];
        s0s[512 + j] = C0[b * 512 + j];
      }
      __syncthreads();
      if (tid < 200) {                     // 2 threads per region (k halves)
        int r = tid >> 1, hf = tid & 1;
        const float4* wp = (const float4*)(aWT + (size_t)r * 1024 + hf * 512);
        const float4* sp = (const float4*)(s0s + hf * 512);
        float a2 = 0.f;
        #pragma unroll 8
        for (int k4 = 0; k4 < 128; k4++) {
          float4 wq = wp[k4], sq = sp[k4];
          a2 += wq.x * sq.x + wq.y * sq.y + wq.z * sq.z + wq.w * sq.w;
        }
        sc[tid] = a2;
      }
      __syncthreads();
      if (tid < 128) al[tid] = -3.4e38f;
      if (tid < 100) al[tid] = sc[2 * tid] + sc[2 * tid + 1] + ab[tid];
      __syncthreads();
      if (tid < 128) sc[tid] = al[tid];
      __syncthreads();
      for (int off = 64; off; off >>= 1) {
        if (tid < off) sc[tid] = fmaxf(sc[tid], sc[tid + off]);
        __syncthreads();
      }
      float mx = sc[0];
      __syncthreads();
      if (tid < 128) {
        float e = (tid < 100) ? expf(al[tid] - mx) : 0.f;
        al[tid] = e; sc[tid] = e;
      }
      __syncthreads();
      for (int off = 64; off; off >>= 1) {
        if (tid < off) sc[tid] += sc[tid + off];
        __syncthreads();
      }
      float inv = 1.f / sc[0];
      // ---- ctx: 4-wave r-split (25 r each), lane covers d = {ln*4, 256+ln*4}
      {
        const float* fb = feat + (size_t)b * RR * 512;
        f32x4 ac0 = {}, ac1 = {};
        int rbase = wv * 25;
        #pragma unroll 5
        for (int ri = 0; ri < 25; ri++) {
          int r = rbase + ri;
          float a = al[r];
          const float* row = fb + (size_t)r * 512;
          float4 v0 = *(const float4*)&row[ln * 4];
          float4 v1 = *(const float4*)&row[256 + ln * 4];
          ac0[0] += a * v0.x; ac0[1] += a * v0.y;
          ac0[2] += a * v0.z; ac0[3] += a * v0.w;
          ac1[0] += a * v1.x; ac1[1] += a * v1.y;
          ac1[2] += a * v1.z; ac1[3] += a * v1.w;
        }
        #pragma unroll
        for (int k = 0; k < 4; k++) {
          zs[wv * 512 + ln * 4 + k]       = ac0[k];
          zs[wv * 512 + 256 + ln * 4 + k] = ac1[k];
        }
        __syncthreads();
        #pragma unroll
        for (int p = 0; p < 2; p++) {
          int dd = p * 256 + tid;
          float s = zs[dd] + zs[512 + dd] + zs[1024 + dd] + zs[1536 + dd];
          CCHp[b * 1536 + 512 + dd] = f2bf(s * inv);
        }
      }
      __syncthreads();
    }
    GSYNC();

    // ---- z1+act1: A = buf(t)[0:1536) contiguous; h1(t) -> buf(t+1)[1024+] ----
    LSTM_PHASE(CCHp, W1T, 1536, 0, X0, b1, C1, CCHq + 1024, (float*)0,
               H1A + (size_t)t * BB * DD);

    // ---- z0(t+1)+act0: A = buf(t)[0:512); h0(t+1) -> buf(t+1)[0+] ----
    if (t + 1 < TT) {
      LSTM_PHASE(CCHp, W0hT, 512, 1, X0 + (size_t)(t + 1) * BB * NG, b1,
                 C0, CCHq, H0F, (short*)0);
    }
    GSYNC();
  }
}

// ============ final hidden state ============
// h0(24) in CCH0[0:512) (t=24 even), h1(24) in CCH1[1024:1536) (buf(25)).
__global__ __launch_bounds__(256) void k_final(
    const short* __restrict__ CCH0, const short* __restrict__ CCH1,
    const float* __restrict__ C0, const float* __restrict__ C1,
    float* __restrict__ out) {
  int idx = blockIdx.x * 256 + threadIdx.x;   // < 262144
  int s = idx >> 17, r = idx & 131071, b = r >> 10, j = r & 1023;
  float v;
  if (s == 0) v = (j < 512) ? bf2f(CCH0[b * 1536 + j])        : C0[b * 512 + j - 512];
  else        v = (j < 512) ? bf2f(CCH1[b * 1536 + 1024 + j]) : C1[b * 512 + j - 512];
  out[(size_t)BB * TT * VV + idx] = v;
}

extern "C" void kernel_launch(void* const* d_in, const int* in_sizes, int n_in,
                              void* d_out, int out_size, void* d_ws, size_t ws_size,
                              hipStream_t stream) {
  const int*   tok  = (const int*)  d_in[0];
  const float* feat = (const float*)d_in[1];
  const float* ihs  = (const float*)d_in[2];
  const float* emb  = (const float*)d_in[3];
  const float* W0   = (const float*)d_in[4];
  const float* b0   = (const float*)d_in[5];
  const float* W1   = (const float*)d_in[6];
  const float* b1   = (const float*)d_in[7];
  const float* aW   = (const float*)d_in[8];
  const float* ab   = (const float*)d_in[9];
  const float* oW   = (const float*)d_in[10];
  const float* ob   = (const float*)d_in[11];
  float* out = (float*)d_out;
  char*  w   = (char*)d_ws;

  // ws layout (bytes); XIN (dead after X0 GEMM) aliases H1A. Total ~57.9 MiB.
  short* XIN  = (short*)w;                    // 3200x1024 bf16 (6,553,600 B)
  short* H1A  = (short*)w;                    // 3200x512  bf16 (alias)
  float* X0   = (float*)(w + 6553600);        // 3200x2048 f32 (26,214,400 B)
  float* POOL = (float*)(w + 32768000);       // 128x512   f32
  short* CCH0 = (short*)(w + 33030144);       // 128x1536  bf16 [h0|ctx|h1]
  short* CCH1 = (short*)(w + 33423360);       // 128x1536  bf16 (ping-pong)
  float* C0   = (float*)(w + 33816576);       // 128x512   f32
  float* C1   = (float*)(w + 34078720);       // 128x512   f32
  float* H0F  = (float*)(w + 34340864);       // 128x512   f32 (h0 for attn)
  short* W0xT = (short*)(w + 34603008);       // 2048x1024 bf16
  short* W0hT = (short*)(w + 38797312);       // 2048x512  bf16
  short* W1T  = (short*)(w + 40894464);       // 2048x1536 bf16
  short* oWT  = (short*)(w + 47185920);       // 10000x512 bf16
  float* aWT  = (float*)(w + 57425920);       // 100x1024  f32 (409,600 B)
  int*   bar  = (int*)  (w + 57835520);       // barrier flags (2048 ints)

  k_init<<<1024, 256, 0, stream>>>(ihs, CCH0, CCH1, C0, C1, bar);
  k_pool<<<256, 256, 0, stream>>>(feat, POOL);
  k_xin<<<12800, 256, 0, stream>>>(tok, emb, POOL, XIN);

  // weight transposes (f32 KxN -> bf16 NxK; attn_W stays f32)
  k_transpose<<<dim3(64, 32), 256, 0, stream>>>(W0, W0xT, 1024, 2048);
  k_transpose<<<dim3(64, 16), 256, 0, stream>>>(W0 + 1024 * NG, W0hT, 512, 2048);
  k_transpose<<<dim3(64, 48), 256, 0, stream>>>(W1, W1T, 1536, 2048);
  k_transpose<<<dim3(313, 16), 256, 0, stream>>>(oW, oWT, 512, 10000);
  k_transpose_f32<<<dim3(4, 32), 256, 0, stream>>>(aW, aWT, 1024, 100);

  // X0 = Xin @ W0[:1024] + b0   (3200 x 2048, K=1024)
  gemm_mfma<<<dim3(16, 25), 256, 0, stream>>>(
      XIN, 1024, W0xT, 1024, b0, X0, NG, NG, 1024, 0);

  // persistent recurrent loop: plain launch, 128 blocks co-resident (<256 CUs)
  k_loop<<<128, 256, 0, stream>>>(X0, W0hT, W1T, b1, aWT, ab, feat,
                                  CCH0, CCH1, C0, C1, H0F, H1A, bar);

  // logits = H1A @ out_W + out_b, remapped to (B,T,V)
  gemm_mfma<<<dim3(79, 25), 256, 0, stream>>>(
      H1A, 512, oWT, 512, ob, out, VV, VV, 512, 1);
  k_final<<<1024, 256, 0, stream>>>(CCH0, CCH1, C0, C1, out);
}

// Round 7
// 1657.134 us; speedup vs baseline: 1.7728x; 1.7728x over previous
//
#include <hip/hip_runtime.h>
#include <math.h>

// Problem constants
#define BB   128      // batch
#define TT   25       // time steps
#define RR   100      // attention regions
#define DD   512
#define VV   10000
#define NG   2048     // 4*H
#define PAD  8        // LDS pad (bf16 elems) for gemm_mfma

typedef short bf8   __attribute__((ext_vector_type(8)));  // 8 bf16 in 4 VGPRs
typedef float f32x4 __attribute__((ext_vector_type(4)));

__device__ __forceinline__ float sigm(float x) { return 1.f / (1.f + expf(-x)); }

__device__ __forceinline__ short f2bf(float f) {        // RNE f32 -> bf16
  unsigned u = __float_as_uint(f);
  u += 0x7fffu + ((u >> 16) & 1u);
  return (short)(u >> 16);
}
__device__ __forceinline__ float bf2f(short h) {
  return __uint_as_float(((unsigned)(unsigned short)h) << 16);
}

// ============ init: scatter initial hidden state ============
// h0_init -> CCH1[0:512) (read by prologue z0); h1_init -> CCH0[1024:1536)
// (read by z1 at t=0). c0/c1 -> C0/C1. Also zero the barrier counter.
__global__ __launch_bounds__(256) void k_init(const float* __restrict__ ihs,
                                              short* __restrict__ CCH0,
                                              short* __restrict__ CCH1,
                                              float* __restrict__ C0,
                                              float* __restrict__ C1,
                                              int* __restrict__ bar) {
  if (blockIdx.x == 0 && threadIdx.x == 0) { bar[0] = 0; bar[1] = 0; }
  int idx = blockIdx.x * 256 + threadIdx.x;     // < 262144
  int s = idx >> 17, r = idx & 131071, b = r >> 10, j = r & 1023;
  float v = ihs[idx];
  if (s == 0) {
    if (j < 512) CCH1[b * 1536 + j] = f2bf(v);
    else         C0[b * 512 + (j - 512)] = v;
  } else {
    if (j < 512) CCH0[b * 1536 + 1024 + j] = f2bf(v);
    else         C1[b * 512 + (j - 512)] = v;
  }
}

// ============ cnn pooled: max over first 10 regions ============
__global__ __launch_bounds__(256) void k_pool(const float* __restrict__ feat,
                                              float* __restrict__ pool) {
  int idx = blockIdx.x * 256 + threadIdx.x;     // < 65536
  int b = idx >> 9, d = idx & 511;
  float m = -3.4e38f;
  #pragma unroll
  for (int r = 0; r < 10; r++)
    m = fmaxf(m, feat[((size_t)b * RR + r) * 512 + d]);
  pool[idx] = m;
}

// ============ Xin (3200 x 1024 bf16): [emb(tok[b,t]) | pooled[b]], row m=t*128+b
__global__ __launch_bounds__(256) void k_xin(const int* __restrict__ tok,
                                             const float* __restrict__ emb,
                                             const float* __restrict__ pool,
                                             short* __restrict__ xin) {
  int idx = blockIdx.x * 256 + threadIdx.x;     // < 3,276,800
  int m = idx >> 10, k = idx & 1023;
  int t = m >> 7, b = m & 127;
  float v;
  if (k < 512) v = emb[(size_t)tok[b * TT + t] * 512 + k];
  else         v = pool[b * 512 + (k - 512)];
  xin[idx] = f2bf(v);
}

// ============ tiled transpose + f32->bf16: in (K x N) -> out (N x K) ============
__global__ __launch_bounds__(256) void k_transpose(const float* __restrict__ in,
                                                   short* __restrict__ out,
                                                   int K, int N) {
  __shared__ float tile[32][33];
  int kt = blockIdx.y * 32, nt = blockIdx.x * 32;
  int tx = threadIdx.x & 31, ty = threadIdx.x >> 5;   // 32 x 8
  #pragma unroll
  for (int i = 0; i < 32; i += 8) {
    int k = kt + ty + i, n = nt + tx;
    tile[ty + i][tx] = (n < N) ? in[(size_t)k * N + n] : 0.f;
  }
  __syncthreads();
  #pragma unroll
  for (int i = 0; i < 32; i += 8) {
    int n = nt + ty + i, k = kt + tx;
    if (n < N) out[(size_t)n * K + k] = f2bf(tile[tx][ty + i]);
  }
}

// same, f32 out (for attn_W so score dot stays f32 and reads are contiguous)
__global__ __launch_bounds__(256) void k_transpose_f32(const float* __restrict__ in,
                                                       float* __restrict__ out,
                                                       int K, int N) {
  __shared__ float tile[32][33];
  int kt = blockIdx.y * 32, nt = blockIdx.x * 32;
  int tx = threadIdx.x & 31, ty = threadIdx.x >> 5;
  #pragma unroll
  for (int i = 0; i < 32; i += 8) {
    int k = kt + ty + i, n = nt + tx;
    tile[ty + i][tx] = (n < N) ? in[(size_t)k * N + n] : 0.f;
  }
  __syncthreads();
  #pragma unroll
  for (int i = 0; i < 32; i += 8) {
    int n = nt + ty + i, k = kt + tx;
    if (n < N) out[(size_t)n * K + k] = tile[tx][ty + i];
  }
}

// ============ big MFMA GEMM: C(MxN f32) = A(MxK bf16) @ BT(NxK bf16)^T + bias
// 128x128 tile, BK=64, 256 thr / 4 waves, each wave 64x64 (4x4 frags 16x16x32).
// mode 0: C[m*ldc+n] = acc+bias   mode 1: logits remap out[b*T*V + t*V + n]
__global__ __launch_bounds__(256) void gemm_mfma(
    const short* __restrict__ A, int lda,
    const short* __restrict__ BT, int ldb,
    const float* __restrict__ bias,
    float* __restrict__ C, int ldc,
    int N, int K, int mode) {
  __shared__ short As[128][64 + PAD];
  __shared__ short Bs[128][64 + PAD];
  const int tid = threadIdx.x;
  const int wv = tid >> 6, ln = tid & 63;
  const int m0 = blockIdx.y * 128, n0 = blockIdx.x * 128;
  const int mw = (wv & 1) * 64, nw = (wv >> 1) * 64;
  const int lrow = ln & 15, quad = ln >> 4, lk8 = quad * 8;

  f32x4 acc[4][4] = {};
  for (int k0 = 0; k0 < K; k0 += 64) {
    #pragma unroll
    for (int v = 0; v < 4; v++) {                 // A: 128x64 = 1024 vecs
      int f = v * 256 + tid, r = f >> 3, kk = (f & 7) * 8;
      *(uint4*)&As[r][kk] = *(const uint4*)&A[(size_t)(m0 + r) * lda + k0 + kk];
    }
    #pragma unroll
    for (int v = 0; v < 4; v++) {                 // B^T: 128 n-rows x 64 k
      int f = v * 256 + tid, r = f >> 3, kk = (f & 7) * 8;
      int n = n0 + r;
      uint4 val{0, 0, 0, 0};
      if (n < N) val = *(const uint4*)&BT[(size_t)n * ldb + k0 + kk];
      *(uint4*)&Bs[r][kk] = val;
    }
    __syncthreads();
    #pragma unroll
    for (int ks = 0; ks < 64; ks += 32) {
      bf8 af[4], bf[4];
      #pragma unroll
      for (int i = 0; i < 4; i++)
        af[i] = *(const bf8*)&As[mw + i * 16 + lrow][ks + lk8];
      #pragma unroll
      for (int j = 0; j < 4; j++)
        bf[j] = *(const bf8*)&Bs[nw + j * 16 + lrow][ks + lk8];
      #pragma unroll
      for (int i = 0; i < 4; i++)
        #pragma unroll
        for (int j = 0; j < 4; j++)
          acc[i][j] = __builtin_amdgcn_mfma_f32_16x16x32_bf16(
              af[i], bf[j], acc[i][j], 0, 0, 0);
    }
    __syncthreads();
  }
  #pragma unroll
  for (int i = 0; i < 4; i++) {
    #pragma unroll
    for (int j = 0; j < 4; j++) {
      #pragma unroll
      for (int r = 0; r < 4; r++) {
        int m = m0 + mw + i * 16 + quad * 4 + r;
        int n = n0 + nw + j * 16 + lrow;
        if (n < N) {
          float v = acc[i][j][r] + (bias ? bias[n] : 0.f);
          if (mode == 0) C[(size_t)m * ldc + n] = v;
          else {
            int t = m >> 7, b = m & 127;
            C[(size_t)b * (TT * VV) + (size_t)t * VV + n] = v;
          }
        }
      }
    }
  }
}

// ============ fused per-step GEMM + LSTM activation (MACRO — no LDS pointers
// cross a function boundary; all __shared__ accesses are direct array refs).
// Block (m0 = 32-row batch slice, j0 = 16-col hidden slice) computes z for ALL
// 4 gates (n = g*512 + j0..j0+15) over full K from ONE contiguous A (stride
// 1536), exchanges z via zs LDS, applies the LSTM cell. K staged in 256 chunks.
// HAS_X: 1 -> add XROW (x-part incl bias), 0 -> add BIASP.
#define LSTM_PHASE(APTR, BTPTR, KTOT, HAS_X, XROW, BIASP, CSTP, HDSTP,        \
                   H0FP, H1ATP)                                               \
  {                                                                           \
    f32x4 acc0 = {}, acc1 = {};                                               \
    for (int k0 = 0; k0 < (KTOT); k0 += 256) {                                \
      _Pragma("unroll")                                                       \
      for (int v = 0; v < 4; v++) {             /* A: 32 x 256 */             \
        int f = v * 256 + tid, r = f >> 5, c = (f & 31) * 8;                  \
        *(uint4*)&As[r][c] =                                                  \
            *(const uint4*)&(APTR)[(size_t)(m0 + r) * 1536 + k0 + c];         \
      }                                                                       \
      _Pragma("unroll")                                                       \
      for (int v = 0; v < 8; v++) {             /* B^T gate-sliced: 64x256 */ \
        int f = v * 256 + tid, r = f >> 5, c = (f & 31) * 8;                  \
        int n = ((r >> 4) << 9) + j0 + (r & 15);                              \
        *(uint4*)&Bs[r][c] =                                                  \
            *(const uint4*)&(BTPTR)[(size_t)n * (KTOT) + k0 + c];             \
      }                                                                       \
      __syncthreads();                                                        \
      _Pragma("unroll")                                                       \
      for (int ks = 0; ks < 256; ks += 32) {    /* wave wv owns gate wv */    \
        bf8 a0 = *(const bf8*)&As[lrow][ks + lk8];                            \
        bf8 a1 = *(const bf8*)&As[16 + lrow][ks + lk8];                       \
        bf8 bb = *(const bf8*)&Bs[wv * 16 + lrow][ks + lk8];                  \
        acc0 = __builtin_amdgcn_mfma_f32_16x16x32_bf16(a0, bb, acc0, 0,0,0);  \
        acc1 = __builtin_amdgcn_mfma_f32_16x16x32_bf16(a1, bb, acc1, 0,0,0);  \
      }                                                                       \
      __syncthreads();                                                        \
    }                                                                         \
    _Pragma("unroll")                                                         \
    for (int r = 0; r < 4; r++) {                                             \
      zs[wv * 512 + (quad * 4 + r) * 16 + lrow] = acc0[r];                    \
      zs[wv * 512 + (16 + quad * 4 + r) * 16 + lrow] = acc1[r];               \
    }                                                                         \
    __syncthreads();                                                          \
    _Pragma("unroll")                                                         \
    for (int e = 0; e < 2; e++) {               /* 512 outputs, 2/thread */   \
      int o = e * 256 + tid, mm = o >> 4, jj = o & 15;                        \
      int b = m0 + mm, j = j0 + jj;                                           \
      float zi = zs[mm * 16 + jj];                                            \
      float zf = zs[512 + mm * 16 + jj];                                      \
      float zo = zs[1024 + mm * 16 + jj];                                     \
      float zg = zs[1536 + mm * 16 + jj];                                     \
      if (HAS_X) {                                                            \
        const float* q = (XROW) + (size_t)b * NG + j;                         \
        zi += q[0]; zf += q[512]; zo += q[1024]; zg += q[1536];               \
      } else {                                                                \
        zi += (BIASP)[j];        zf += (BIASP)[512 + j];                      \
        zo += (BIASP)[1024 + j]; zg += (BIASP)[1536 + j];                     \
      }                                                                       \
      float c  = (CSTP)[b * 512 + j];                                         \
      float cn = sigm(zf) * c + sigm(zi) * tanhf(zg);                         \
      float hn = sigm(zo) * tanhf(cn);                                        \
      (CSTP)[b * 512 + j] = cn;                                               \
      short hb = f2bf(hn);                                                    \
      (HDSTP)[b * 1536 + j] = hb;                                             \
      if (H0FP)  ((float*)(H0FP))[b * 512 + j] = hn;                          \
      if (H1ATP) ((short*)(H1ATP))[(size_t)b * 512 + j] = hb;                 \
    }                                                                         \
    __syncthreads();                                                          \
  }

// ---- grid barrier: monotonic arrival counter. Arrival = one device-scope
// atomicAdd; poll = RELAXED agent-scope atomic LOAD (no RMW queue serialization,
// no per-iteration cache maintenance — ACQUIRE-per-poll caused L2 flush storms).
// Acquire is the single __threadfence() after spin exit. Fallback RMW every
// 1024 polls guards against staleness. 128 blocks co-resident (plain launch,
// grid < CU count).
#define GSYNC()                                                               \
  {                                                                           \
    phase++;                                                                  \
    __syncthreads();                                                          \
    if (tid == 0) {                                                           \
      __threadfence();                                                        \
      atomicAdd(&bar[0], 1);                                                  \
      int it = 0;                                                             \
      while (__hip_atomic_load(&bar[0], __ATOMIC_RELAXED,                     \
                               __HIP_MEMORY_SCOPE_AGENT) < phase * 128) {     \
        if (((++it) & 1023) == 0) atomicAdd(&bar[0], 0);                      \
      }                                                                       \
      __threadfence();                                                        \
    }                                                                         \
    __syncthreads();                                                          \
  }

// ============ persistent t-loop: 1 plain launch, 128 co-resident blocks ======
// Buffers: buf(t) = (t&1)?CCH1:CCH0 holds [h0(t)|ctx(t)|h1(t-1)].
// Per step: [attn] gsync [z1+act1 ; z0(t+1)+act0] gsync  (z0(0) = prologue).
// act1 writes h1(t) into buf(t+1)[1024+]; act0 writes h0(t+1) into buf(t+1)[0+].
__global__ __launch_bounds__(256) void k_loop(
    const float* X0, const short* W0hT, const short* W1T, const float* b1,
    const float* aWT, const float* ab, const float* feat,
    short* CCH0, short* CCH1, float* C0, float* C1,
    float* H0F, short* H1A, int* bar) {
  __shared__ short As[32][264];
  __shared__ short Bs[64][264];
  __shared__ float zs[2048];
  const int tid = threadIdx.x, bid = blockIdx.x;
  const int m0 = (bid >> 5) * 32, j0 = (bid & 31) * 16;
  const int wv = tid >> 6, ln = tid & 63;
  const int lrow = ln & 15, quad = ln >> 4, lk8 = quad * 8;
  int phase = 0;

  // prologue: z0(0)+act0  (A = h0_init in CCH1[0:512), writes h0(0)->CCH0, H0F)
  LSTM_PHASE(CCH1, W0hT, 512, 1, X0, b1, C0, CCH0, H0F, (short*)0);
  GSYNC();

  #pragma unroll 1
  for (int t = 0; t < TT; t++) {
    short* CCHp = (t & 1) ? CCH1 : CCH0;   // buf(t)
    short* CCHq = (t & 1) ? CCH0 : CCH1;   // buf(t+1)

    // ---- attention: block bid handles batch b = bid ----
    {
      float* s0s = zs;                     // 1024
      float* sc  = zs + 1024;              // 256
      float* al  = zs + 1280;              // 128
      int b = bid;
      #pragma unroll
      for (int h = 0; h < 2; h++) {
        int j = h * 256 + tid;
        s0s[j]       = H0F[b * 512 + j];
        s0s[512 + j] = C0[b * 512 + j];
      }
      __syncthreads();
      if (tid < 200) {                     // 2 threads per region (k halves)
        int r = tid >> 1, hf = tid & 1;
        const float4* wp = (const float4*)(aWT + (size_t)r * 1024 + hf * 512);
        const float4* sp = (const float4*)(s0s + hf * 512);
        float a2 = 0.f;
        #pragma unroll 8
        for (int k4 = 0; k4 < 128; k4++) {
          float4 wq = wp[k4], sq = sp[k4];
          a2 += wq.x * sq.x + wq.y * sq.y + wq.z * sq.z + wq.w * sq.w;
        }
        sc[tid] = a2;
      }
      __syncthreads();
      if (tid < 128) al[tid] = -3.4e38f;
      if (tid < 100) al[tid] = sc[2 * tid] + sc[2 * tid + 1] + ab[tid];
      __syncthreads();
      if (tid < 128) sc[tid] = al[tid];
      __syncthreads();
      for (int off = 64; off; off >>= 1) {
        if (tid < off) sc[tid] = fmaxf(sc[tid], sc[tid + off]);
        __syncthreads();
      }
      float mx = sc[0];
      __syncthreads();
      if (tid < 128) {
        float e = (tid < 100) ? expf(al[tid] - mx) : 0.f;
        al[tid] = e; sc[tid] = e;
      }
      __syncthreads();
      for (int off = 64; off; off >>= 1) {
        if (tid < off) sc[tid] += sc[tid + off];
        __syncthreads();
      }
      float inv = 1.f / sc[0];
      #pragma unroll
      for (int h = 0; h < 2; h++) {
        int d = h * 256 + tid;
        float a2 = 0.f;
        for (int r = 0; r < RR; r++)
          a2 += al[r] * feat[((size_t)b * RR + r) * 512 + d];
        CCHp[b * 1536 + 512 + d] = f2bf(a2 * inv);
      }
      __syncthreads();
    }
    GSYNC();

    // ---- z1+act1: A = buf(t)[0:1536) contiguous; h1(t) -> buf(t+1)[1024+] ----
    LSTM_PHASE(CCHp, W1T, 1536, 0, X0, b1, C1, CCHq + 1024, (float*)0,
               H1A + (size_t)t * BB * DD);

    // ---- z0(t+1)+act0: A = buf(t)[0:512); h0(t+1) -> buf(t+1)[0+] ----
    if (t + 1 < TT) {
      LSTM_PHASE(CCHp, W0hT, 512, 1, X0 + (size_t)(t + 1) * BB * NG, b1,
                 C0, CCHq, H0F, (short*)0);
    }
    GSYNC();
  }
}

// ============ final hidden state ============
// h0(24) in CCH0[0:512) (t=24 even), h1(24) in CCH1[1024:1536) (buf(25)).
__global__ __launch_bounds__(256) void k_final(
    const short* __restrict__ CCH0, const short* __restrict__ CCH1,
    const float* __restrict__ C0, const float* __restrict__ C1,
    float* __restrict__ out) {
  int idx = blockIdx.x * 256 + threadIdx.x;   // < 262144
  int s = idx >> 17, r = idx & 131071, b = r >> 10, j = r & 1023;
  float v;
  if (s == 0) v = (j < 512) ? bf2f(CCH0[b * 1536 + j])        : C0[b * 512 + j - 512];
  else        v = (j < 512) ? bf2f(CCH1[b * 1536 + 1024 + j]) : C1[b * 512 + j - 512];
  out[(size_t)BB * TT * VV + idx] = v;
}

extern "C" void kernel_launch(void* const* d_in, const int* in_sizes, int n_in,
                              void* d_out, int out_size, void* d_ws, size_t ws_size,
                              hipStream_t stream) {
  const int*   tok  = (const int*)  d_in[0];
  const float* feat = (const float*)d_in[1];
  const float* ihs  = (const float*)d_in[2];
  const float* emb  = (const float*)d_in[3];
  const float* W0   = (const float*)d_in[4];
  const float* b0   = (const float*)d_in[5];
  const float* W1   = (const float*)d_in[6];
  const float* b1   = (const float*)d_in[7];
  const float* aW   = (const float*)d_in[8];
  const float* ab   = (const float*)d_in[9];
  const float* oW   = (const float*)d_in[10];
  const float* ob   = (const float*)d_in[11];
  float* out = (float*)d_out;
  char*  w   = (char*)d_ws;

  // ws layout (bytes); XIN (dead after X0 GEMM) aliases H1A. Total ~57.8 MiB.
  short* XIN  = (short*)w;                    // 3200x1024 bf16 (6,553,600 B)
  short* H1A  = (short*)w;                    // 3200x512  bf16 (alias)
  float* X0   = (float*)(w + 6553600);        // 3200x2048 f32 (26,214,400 B)
  float* POOL = (float*)(w + 32768000);       // 128x512   f32
  short* CCH0 = (short*)(w + 33030144);       // 128x1536  bf16 [h0|ctx|h1]
  short* CCH1 = (short*)(w + 33423360);       // 128x1536  bf16 (ping-pong)
  float* C0   = (float*)(w + 33816576);       // 128x512   f32
  float* C1   = (float*)(w + 34078720);       // 128x512   f32
  float* H0F  = (float*)(w + 34340864);       // 128x512   f32 (h0 for attn)
  short* W0xT = (short*)(w + 34603008);       // 2048x1024 bf16
  short* W0hT = (short*)(w + 38797312);       // 2048x512  bf16
  short* W1T  = (short*)(w + 40894464);       // 2048x1536 bf16
  short* oWT  = (short*)(w + 47185920);       // 10000x512 bf16
  float* aWT  = (float*)(w + 57425920);       // 100x1024  f32 (409,600 B)
  int*   bar  = (int*)  (w + 57835520);       // barrier counter

  k_init<<<1024, 256, 0, stream>>>(ihs, CCH0, CCH1, C0, C1, bar);
  k_pool<<<256, 256, 0, stream>>>(feat, POOL);
  k_xin<<<12800, 256, 0, stream>>>(tok, emb, POOL, XIN);

  // weight transposes (f32 KxN -> bf16 NxK; attn_W stays f32)
  k_transpose<<<dim3(64, 32), 256, 0, stream>>>(W0, W0xT, 1024, 2048);
  k_transpose<<<dim3(64, 16), 256, 0, stream>>>(W0 + 1024 * NG, W0hT, 512, 2048);
  k_transpose<<<dim3(64, 48), 256, 0, stream>>>(W1, W1T, 1536, 2048);
  k_transpose<<<dim3(313, 16), 256, 0, stream>>>(oW, oWT, 512, 10000);
  k_transpose_f32<<<dim3(4, 32), 256, 0, stream>>>(aW, aWT, 1024, 100);

  // X0 = Xin @ W0[:1024] + b0   (3200 x 2048, K=1024)
  gemm_mfma<<<dim3(16, 25), 256, 0, stream>>>(
      XIN, 1024, W0xT, 1024, b0, X0, NG, NG, 1024, 0);

  // persistent recurrent loop: plain launch, 128 blocks co-resident (<256 CUs)
  k_loop<<<128, 256, 0, stream>>>(X0, W0hT, W1T, b1, aWT, ab, feat,
                                  CCH0, CCH1, C0, C1, H0F, H1A, bar);

  // logits = H1A @ out_W + out_b, remapped to (B,T,V)
  gemm_mfma<<<dim3(79, 25), 256, 0, stream>>>(
      H1A, 512, oWT, 512, ob, out, VV, VV, 512, 1);
  k_final<<<1024, 256, 0, stream>>>(CCH0, CCH1, C0, C1, out);
}